// Round 10
// baseline (361.920 us; speedup 1.0000x reference)
//
#include <hip/hip_runtime.h>
#include <hip/hip_bf16.h>
#include <cstdint>
#include <cstddef>

// Problem constants: B=1, L=4096, DM=1024, NH=16, DH=64, w=512, C=8
#define L_ 4096
#define DM_ 1024
#define NH_ 16
#define DH_ 64
#define W_ 512
#define C_ 8
#define W3_ 1536
#define NROWS_ 65536

typedef __attribute__((ext_vector_type(8))) short short8;
typedef __attribute__((ext_vector_type(4))) float f32x4;

__device__ __forceinline__ void async16(const void* g, void* l) {
    __builtin_amdgcn_global_load_lds(
        (const __attribute__((address_space(1))) unsigned int*)g,
        (__attribute__((address_space(3))) unsigned int*)l, 16, 0, 0);
}

#if __has_builtin(__builtin_amdgcn_exp2f)
#define FEXP2(x) __builtin_amdgcn_exp2f(x)
#else
#define FEXP2(x) exp2f(x)
#endif

// ---------------------------------------------------------------------------
// Input-dtype detector (fp32 vs bf16).
// ---------------------------------------------------------------------------
__device__ __forceinline__ int nanhit(unsigned u) {
    return (((u & 0x7F80u) == 0x7F80u) | (((u >> 16) & 0x7F80u) == 0x7F80u));
}
__global__ __launch_bounds__(256) void detect_kernel(const uint4* __restrict__ q,
                                                     int* __restrict__ flag) {
    __shared__ int s;
    if (threadIdx.x == 0) s = 0;
    __syncthreads();
    int hit = 0;
#pragma unroll
    for (int r = 0; r < 8; ++r) {
        uint4 v = q[threadIdx.x + 256 * r];
        hit |= nanhit(v.x) | nanhit(v.y) | nanhit(v.z) | nanhit(v.w);
    }
    if (__any(hit)) { if ((threadIdx.x & 63) == 0) atomicOr(&s, 1); }
    __syncthreads();
    if (threadIdx.x == 0) flag[0] = s;
}

__device__ __forceinline__ float ldf(const void* X, size_t i, int f32) {
    return f32 ? ((const float*)X)[i] : __bfloat162float(((const __hip_bfloat16*)X)[i]);
}

// ---------------------------------------------------------------------------
// Megaprep (one dispatch): q convert (4096 blocks), Wq^T (256), Wc^T (256),
// Wkv^T (32), kvred build (1536): rows 0..511 = sum of 8 chunks of kv,
// 512..1023 = first chunk, 1024..1535 = last chunk (all bf16).
// ---------------------------------------------------------------------------
__global__ __launch_bounds__(256) void megaprep(const void* __restrict__ q,
                                                const void* __restrict__ kv,
                                                const void* __restrict__ Wq,
                                                const void* __restrict__ Wkv,
                                                const void* __restrict__ Wc,
                                                __hip_bfloat16* __restrict__ qbuf,
                                                __hip_bfloat16* __restrict__ WqT,
                                                __hip_bfloat16* __restrict__ WkvT,
                                                __hip_bfloat16* __restrict__ WcT,
                                                __hip_bfloat16* __restrict__ kvred,
                                                const int* __restrict__ flag) {
    __shared__ float t[64][65];
    const int b = blockIdx.x;
    const int f32 = flag[0];
    const int tid = threadIdx.x;

    if (b < 4096) {
        int i = (b * 256 + tid) * 4;
        if (f32) {
            float4 v = *(const float4*)((const float*)q + i);
            __hip_bfloat162 tmp[2] = {__float22bfloat162_rn({v.x, v.y}),
                                      __float22bfloat162_rn({v.z, v.w})};
            *(short4*)((short*)qbuf + i) = *(const short4*)tmp;
        } else {
            *(short4*)((short*)qbuf + i) = *(const short4*)((const short*)q + i);
        }
    } else if (b < 4640) {
        const void* W;
        __hip_bfloat16* WT;
        int K = 1024, N, n0, k0;
        if (b < 4352) {
            int bx = b - 4096; W = Wq; WT = WqT; N = 1024;
            n0 = (bx & 15) * 64; k0 = (bx >> 4) * 64;
        } else if (b < 4608) {
            int bx = b - 4352; W = Wc; WT = WcT; N = 1024;
            n0 = (bx & 15) * 64; k0 = (bx >> 4) * 64;
        } else {
            int bx = b - 4608; W = Wkv; WT = WkvT; N = 128;
            n0 = (bx & 1) * 64; k0 = (bx >> 1) * 64;
        }
        const int tx = tid & 63;
        const int ty = tid >> 6;
#pragma unroll
        for (int r = 0; r < 16; ++r) {
            int k = ty + r * 4;
            t[k][tx] = ldf(W, (size_t)(k0 + k) * N + n0 + tx, f32);
        }
        __syncthreads();
#pragma unroll
        for (int r = 0; r < 16; ++r) {
            int n = ty + r * 4;
            WT[(size_t)(n0 + n) * K + k0 + tx] = __float2bfloat16(t[tx][n]);
        }
    } else {
        int y2 = b - 4640;          // 0..1535
        int c = tid * 4;
        float a0 = 0.f, a1 = 0.f, a2 = 0.f, a3 = 0.f;
        if (y2 < 512) {
#pragma unroll
            for (int z = 0; z < C_; ++z) {
                size_t base = (size_t)(z * W_ + y2) * 1024 + c;
                a0 += ldf(kv, base + 0, f32);
                a1 += ldf(kv, base + 1, f32);
                a2 += ldf(kv, base + 2, f32);
                a3 += ldf(kv, base + 3, f32);
            }
        } else {
            int row = (y2 < 1024) ? (y2 - 512) : (3584 + y2 - 1024);
            size_t base = (size_t)row * 1024 + c;
            a0 = ldf(kv, base + 0, f32);
            a1 = ldf(kv, base + 1, f32);
            a2 = ldf(kv, base + 2, f32);
            a3 = ldf(kv, base + 3, f32);
        }
        __hip_bfloat162 tmp[2] = {__float22bfloat162_rn({a0, a1}),
                                  __float22bfloat162_rn({a2, a3})};
        *(short4*)((short*)kvred + (size_t)y2 * 1024 + c) = *(const short4*)tmp;
    }
}

// ---------------------------------------------------------------------------
// MFMA GEMM: C[M,N] = alpha * A[M,K] @ BT[N,K]^T, bf16 in, fp32 accum.
// 128x64 tile, BK=64 (two BK=32 sub-tiles). plain=0: XCD swizzle mapping
// (all 8 n-tiles of an m-tile on XCD mt&7).
// cMode: 0 = follow flag (fp32 if flag else bf16), 1 = fp32, 2 = bf16
// ---------------------------------------------------------------------------
__global__ __launch_bounds__(256) void gemm_bt_mfma(const __hip_bfloat16* __restrict__ A,
                                                    const __hip_bfloat16* __restrict__ BT,
                                                    void* __restrict__ C,
                                                    int M, int N, int K, float alpha,
                                                    int cMode, int ntiles, int plain,
                                                    const int* __restrict__ flag) {
    __shared__ __hip_bfloat16 Asl[2][128 * 32];
    __shared__ __hip_bfloat16 Bsl[2][64 * 32];

    const int bid = blockIdx.x;
    int mt, nt;
    if (plain) { mt = bid / ntiles; nt = bid % ntiles; }
    else {
        int g = bid / (8 * ntiles);
        int rem = bid % (8 * ntiles);
        mt = g * 8 + (rem & 7);
        nt = rem >> 3;
    }
    const int m0 = mt * 128;
    const int n0 = nt * 64;

    const int tid = threadIdx.x;
    const int lane = tid & 63;
    const int wv = tid >> 6;
    const int wm = wv >> 1;
    const int wn = wv & 1;
    const int col = lane & 15;
    const int quad = lane >> 4;

    const int srow = lane >> 2;
    const int scol = (lane & 3) * 8;
    const __hip_bfloat16* Ag = A + (size_t)m0 * K;
    const __hip_bfloat16* Bg = BT + (size_t)n0 * K;

    f32x4 acc[4][2] = {};

    for (int k0 = 0; k0 < K; k0 += 64) {
#pragma unroll
        for (int h = 0; h < 2; ++h) {
            int arow = wv * 32 + h * 16 + srow;
#pragma unroll
            for (int kc = 0; kc < 2; ++kc)
                async16(Ag + (size_t)arow * K + k0 + kc * 32 + scol,
                        &Asl[kc][arow * 32 + scol]);
        }
        {
            int brow = wv * 16 + srow;
#pragma unroll
            for (int kc = 0; kc < 2; ++kc)
                async16(Bg + (size_t)brow * K + k0 + kc * 32 + scol,
                        &Bsl[kc][brow * 32 + scol]);
        }
        __syncthreads();

#pragma unroll
        for (int kc = 0; kc < 2; ++kc) {
            short8 af[4], bfr[2];
#pragma unroll
            for (int i = 0; i < 4; ++i)
                af[i] = *(const short8*)(&Asl[kc][(wm * 64 + i * 16 + col) * 32 + quad * 8]);
#pragma unroll
            for (int j = 0; j < 2; ++j)
                bfr[j] = *(const short8*)(&Bsl[kc][(wn * 32 + j * 16 + col) * 32 + quad * 8]);
#pragma unroll
            for (int am = 0; am < 4; ++am)
#pragma unroll
                for (int bn = 0; bn < 2; ++bn)
                    acc[am][bn] = __builtin_amdgcn_mfma_f32_16x16x32_bf16(af[am], bfr[bn], acc[am][bn], 0, 0, 0);
        }
        __syncthreads();
    }

    int cF = (cMode == 1) ? 1 : ((cMode == 2) ? 0 : flag[0]);
#pragma unroll
    for (int am = 0; am < 4; ++am)
#pragma unroll
        for (int bn = 0; bn < 2; ++bn)
#pragma unroll
            for (int r = 0; r < 4; ++r) {
                size_t ci = (size_t)(m0 + wm * 64 + am * 16 + quad * 4 + r) * N
                            + n0 + wn * 32 + bn * 16 + col;
                float v = acc[am][bn][r] * alpha;
                if (cF) ((float*)C)[ci] = v;
                else ((__hip_bfloat16*)C)[ci] = __float2bfloat16(v);
            }
}

// ---------------------------------------------------------------------------
// Combine kvp_red [1536][128] fp32 -> bf16 Kb [1536][64] (natural order) and
// Vt [64][1536] with the R8 key permutation within 64-groups:
// p = ((i&15)<<2) | (i>>4), matching attn P LDS layout (pos = col*4 + f).
// kvp_red rows: y = sum-all, 512+y = first chunk, 1024+y = last chunk.
// ---------------------------------------------------------------------------
__global__ __launch_bounds__(256) void sums_kernel(const float* __restrict__ kvp_red,
                                                   __hip_bfloat16* __restrict__ Kb,
                                                   __hip_bfloat16* __restrict__ Vt) {
    int t = blockIdx.x * 256 + threadIdx.x;
    int d = t & 63;
    int y = t >> 6;

    float kc = kvp_red[(size_t)y * 128 + d];
    float kf = kvp_red[(size_t)(512 + y) * 128 + d];
    float kl = kvp_red[(size_t)(1024 + y) * 128 + d];
    float vc = kvp_red[(size_t)y * 128 + 64 + d];
    float vf = kvp_red[(size_t)(512 + y) * 128 + 64 + d];
    float vl = kvp_red[(size_t)(1024 + y) * 128 + 64 + d];

    float kvals[3] = {kc - kl, kc, kc - kf};
    float vvals[3] = {vc - vl, vc, vc - vf};
#pragma unroll
    for (int e = 0; e < 3; ++e) {
        int key = e * W_ + y;
        Kb[(size_t)key * 64 + d] = __float2bfloat16(kvals[e]);
        int g = key >> 6;
        int i = key & 63;
        int p = ((i & 15) << 2) | (i >> 4);
        Vt[(size_t)d * W3_ + g * 64 + p] = __float2bfloat16(vvals[e]);
    }
}

// ---------------------------------------------------------------------------
// Flash MFMA attention (R8 structure): block = 64 rows, 4 waves key-split
// (384 keys each), Q persistent in regs, P via wave-private LDS, fixed-max
// exp2 softmax, LDS reduction epilogue.
// R10 additions: (a) cross-tile K double-buffer + early V loads (removes the
// per-tile K-load latency exposure), (b) XCD-aligned block swizzle so qb
// producer GEMM / attn / ctx consumer GEMM share an XCD per m-tile.
// ---------------------------------------------------------------------------
#define PSTRIDE 72
__global__ __launch_bounds__(256, 2) void attn_kernel(const __hip_bfloat16* __restrict__ qb,
                                                      const __hip_bfloat16* __restrict__ Kb,
                                                      const __hip_bfloat16* __restrict__ Vt,
                                                      __hip_bfloat16* __restrict__ ctx) {
    __shared__ __align__(16) char smem[36864 + 1024];
    float* Ls = (float*)smem;
    float* lsum = (float*)(smem + 36864);

    const int tid = threadIdx.x;
    const int lane = tid & 63;
    const int wv = tid >> 6;
    // XCD swizzle: consumer of qb m-tile j sits on XCD j&7 (matches gemm map)
    const int B = blockIdx.x;
    const int j = (B & 7) + 8 * (B >> 4);
    const int m0 = (((B >> 3) & 1) + 2 * j) * 64;
    const int col = lane & 15;
    const int quad = lane >> 4;
    __hip_bfloat16* pw = (__hip_bfloat16*)smem + wv * (64 * PSTRIDE);

    short8 qf[4][2];
#pragma unroll
    for (int rg = 0; rg < 4; ++rg) {
        const __hip_bfloat16* qp = qb + (size_t)(m0 + rg * 16 + col) * 64 + quad * 8;
        qf[rg][0] = *(const short8*)(qp);
        qf[rg][1] = *(const short8*)(qp + 32);
    }

    f32x4 O[4][4] = {};
    float lrow[4][4] = {};

    // K double buffer; prologue loads tile 0
    short8 kb[2][2][4];   // [buf][dchunk][g]
    {
        const int kt = wv * 384;
#pragma unroll
        for (int g = 0; g < 4; ++g) {
            const __hip_bfloat16* kp = Kb + (size_t)(kt + g * 16 + col) * 64 + quad * 8;
            kb[0][0][g] = *(const short8*)(kp);
            kb[0][1][g] = *(const short8*)(kp + 32);
        }
    }

#pragma unroll
    for (int t = 0; t < 6; ++t) {
        const int cur = t & 1, nxt = cur ^ 1;
        const int kt = wv * 384 + t * 64;

        // prefetch next tile's K into the other buffer
        if (t < 5) {
            const int ktn = kt + 64;
#pragma unroll
            for (int g = 0; g < 4; ++g) {
                const __hip_bfloat16* kp = Kb + (size_t)(ktn + g * 16 + col) * 64 + quad * 8;
                kb[nxt][0][g] = *(const short8*)(kp);
                kb[nxt][1][g] = *(const short8*)(kp + 32);
            }
        }

        // V loads early (consumed ~500 cyc later, after exp2 + LDS round-trip)
        short8 vb0[4], vb1[4];
#pragma unroll
        for (int f = 0; f < 4; ++f) {
            const __hip_bfloat16* vp = Vt + (size_t)(f * 16 + col) * W3_ + kt + quad * 8;
            vb0[f] = *(const short8*)(vp);
            vb1[f] = *(const short8*)(vp + 32);
        }

        // QK + exp2 + packed P write per row-group (uses resident kb[cur])
#pragma unroll
        for (int rg = 0; rg < 4; ++rg) {
            f32x4 S[4];
#pragma unroll
            for (int f = 0; f < 4; ++f) {
                f32x4 s = {};
                s = __builtin_amdgcn_mfma_f32_16x16x32_bf16(qf[rg][0], kb[cur][0][f], s, 0, 0, 0);
                s = __builtin_amdgcn_mfma_f32_16x16x32_bf16(qf[rg][1], kb[cur][1][f], s, 0, 0, 0);
                S[f] = s;
            }
#pragma unroll
            for (int f = 0; f < 4; ++f)
#pragma unroll
                for (int r = 0; r < 4; ++r) S[f][r] = FEXP2(S[f][r]);
#pragma unroll
            for (int r = 0; r < 4; ++r)
                lrow[rg][r] += (S[0][r] + S[1][r]) + (S[2][r] + S[3][r]);
#pragma unroll
            for (int r = 0; r < 4; ++r) {
                __hip_bfloat162 p01 = __float22bfloat162_rn({S[0][r], S[1][r]});
                __hip_bfloat162 p23 = __float22bfloat162_rn({S[2][r], S[3][r]});
                short4 t4;
                *(__hip_bfloat162*)(&t4.x) = p01;
                *(__hip_bfloat162*)(&t4.z) = p23;
                *(short4*)(pw + (rg * 16 + quad * 4 + r) * PSTRIDE + col * 4) = t4;
            }
        }

        // P read (in-order DS, wave-private) + PV
#pragma unroll
        for (int rg = 0; rg < 4; ++rg) {
            short8 a0 = *(const short8*)(pw + (rg * 16 + col) * PSTRIDE + quad * 8);
            short8 a1 = *(const short8*)(pw + (rg * 16 + col) * PSTRIDE + 32 + quad * 8);
#pragma unroll
            for (int f = 0; f < 4; ++f) {
                O[rg][f] = __builtin_amdgcn_mfma_f32_16x16x32_bf16(a0, vb0[f], O[rg][f], 0, 0, 0);
                O[rg][f] = __builtin_amdgcn_mfma_f32_16x16x32_bf16(a1, vb1[f], O[rg][f], 0, 0, 0);
            }
        }
    }

#pragma unroll
    for (int msk = 1; msk <= 8; msk <<= 1)
#pragma unroll
        for (int rg = 0; rg < 4; ++rg)
#pragma unroll
            for (int r = 0; r < 4; ++r) lrow[rg][r] += __shfl_xor(lrow[rg][r], msk, 64);

    __syncthreads();

    if (col == 0) {
#pragma unroll
        for (int rg = 0; rg < 4; ++rg)
#pragma unroll
            for (int r = 0; r < 4; ++r)
                lsum[wv * 64 + rg * 16 + quad * 4 + r] = lrow[rg][r];
    }

#pragma unroll
    for (int half = 0; half < 2; ++half) {
#pragma unroll
        for (int g = 0; g < 2; ++g) {
            int rg = half * 2 + g;
#pragma unroll
            for (int f = 0; f < 4; ++f)
#pragma unroll
                for (int r = 0; r < 4; ++r)
                    Ls[(wv * 32 + g * 16 + quad * 4 + r) * 66 + f * 16 + col] = O[rg][f][r];
        }
        __syncthreads();
#pragma unroll
        for (int i = 0; i < 8; ++i) {
            int r32 = wv * 8 + i;
            int row = half * 32 + r32;
            float tot = Ls[(0 * 32 + r32) * 66 + lane]
                      + Ls[(1 * 32 + r32) * 66 + lane]
                      + Ls[(2 * 32 + r32) * 66 + lane]
                      + Ls[(3 * 32 + r32) * 66 + lane];
            float ltot = lsum[0 * 64 + row] + lsum[1 * 64 + row]
                       + lsum[2 * 64 + row] + lsum[3 * 64 + row];
            ctx[(size_t)(m0 + row) * 64 + lane] = __float2bfloat16(tot * (1.f / ltot));
        }
        __syncthreads();
    }
}

// ---------------------------------------------------------------------------
// Launch
// ---------------------------------------------------------------------------
extern "C" void kernel_launch(void* const* d_in, const int* in_sizes, int n_in,
                              void* d_out, int out_size, void* d_ws, size_t ws_size,
                              hipStream_t stream) {
    const void* q   = d_in[0];
    const void* kv  = d_in[1];
    const void* Wq  = d_in[2];
    const void* Wkv = d_in[3];
    const void* Wc  = d_in[4];

    char* ws = (char*)d_ws;
    size_t off = 0;
    int* flag = (int*)(ws + off); off += 1024;
    __hip_bfloat16* qbuf   = (__hip_bfloat16*)(ws + off); off += (size_t)L_ * DM_ * 2;     // 8 MB
    __hip_bfloat16* WqT    = (__hip_bfloat16*)(ws + off); off += (size_t)DM_ * DM_ * 2;    // 2 MB
    __hip_bfloat16* WkvT   = (__hip_bfloat16*)(ws + off); off += (size_t)128 * DM_ * 2;    // 256 KB
    __hip_bfloat16* WcT    = (__hip_bfloat16*)(ws + off); off += (size_t)DM_ * DM_ * 2;    // 2 MB
    __hip_bfloat16* qb     = (__hip_bfloat16*)(ws + off); off += (size_t)L_ * DM_ * 2;     // 8 MB
    __hip_bfloat16* kvred  = (__hip_bfloat16*)(ws + off); off += (size_t)1536 * 1024 * 2;  // 3 MB
    float*          kvpred = (float*)(ws + off);          off += (size_t)1536 * 128 * 4;   // 768 KB
    __hip_bfloat16* Kb     = (__hip_bfloat16*)(ws + off); off += (size_t)W3_ * 64 * 2;     // 192 KB
    __hip_bfloat16* Vt     = (__hip_bfloat16*)(ws + off); off += (size_t)64 * W3_ * 2;     // 192 KB
    __hip_bfloat16* ctxb   = (__hip_bfloat16*)(ws + off);                                  // 8 MB

    detect_kernel<<<1, 256, 0, stream>>>((const uint4*)q, flag);

    megaprep<<<6176, 256, 0, stream>>>(q, kv, Wq, Wkv, Wc,
                                       qbuf, WqT, WkvT, WcT, kvred, flag);

    // qb = (q @ Wq) * (1/8)*log2(e), bf16 (exp2-domain logits)
    gemm_bt_mfma<<<512, 256, 0, stream>>>(qbuf, WqT, qb, L_, DM_, DM_,
                                          0.125f * 1.44269504f, 2, 16, 0, flag);
    // kvp_red = kvred @ Wkv, fp32  (M=1536 after chunk-sum commutation)
    gemm_bt_mfma<<<24, 256, 0, stream>>>(kvred, WkvT, kvpred, 1536, 128, DM_,
                                         1.0f, 1, 2, 1, flag);
    sums_kernel<<<128, 256, 0, stream>>>(kvpred, Kb, Vt);
    attn_kernel<<<dim3(NROWS_ / 64), 256, 0, stream>>>(qb, Kb, Vt, ctxb);
    // out = ctx @ Wc, dtype per flag
    gemm_bt_mfma<<<512, 256, 0, stream>>>(ctxb, WcT, d_out, L_, DM_, DM_,
                                          1.0f, 0, 16, 0, flag);
}

// Round 11
// 218.037 us; speedup vs baseline: 1.6599x; 1.6599x over previous
//
#include <hip/hip_runtime.h>
#include <hip/hip_bf16.h>
#include <cstdint>
#include <cstddef>

// Problem constants: B=1, L=4096, DM=1024, NH=16, DH=64, w=512, C=8
#define L_ 4096
#define DM_ 1024
#define NH_ 16
#define DH_ 64
#define W_ 512
#define C_ 8
#define W3_ 1536
#define NROWS_ 65536

typedef __attribute__((ext_vector_type(8))) short short8;
typedef __attribute__((ext_vector_type(4))) float f32x4;

__device__ __forceinline__ void async16(const void* g, void* l) {
    __builtin_amdgcn_global_load_lds(
        (const __attribute__((address_space(1))) unsigned int*)g,
        (__attribute__((address_space(3))) unsigned int*)l, 16, 0, 0);
}

#if __has_builtin(__builtin_amdgcn_exp2f)
#define FEXP2(x) __builtin_amdgcn_exp2f(x)
#else
#define FEXP2(x) exp2f(x)
#endif

// ---------------------------------------------------------------------------
// Input-dtype detector (fp32 vs bf16).
// ---------------------------------------------------------------------------
__device__ __forceinline__ int nanhit(unsigned u) {
    return (((u & 0x7F80u) == 0x7F80u) | (((u >> 16) & 0x7F80u) == 0x7F80u));
}
__global__ __launch_bounds__(256) void detect_kernel(const uint4* __restrict__ q,
                                                     int* __restrict__ flag) {
    __shared__ int s;
    if (threadIdx.x == 0) s = 0;
    __syncthreads();
    int hit = 0;
#pragma unroll
    for (int r = 0; r < 8; ++r) {
        uint4 v = q[threadIdx.x + 256 * r];
        hit |= nanhit(v.x) | nanhit(v.y) | nanhit(v.z) | nanhit(v.w);
    }
    if (__any(hit)) { if ((threadIdx.x & 63) == 0) atomicOr(&s, 1); }
    __syncthreads();
    if (threadIdx.x == 0) flag[0] = s;
}

__device__ __forceinline__ float ldf(const void* X, size_t i, int f32) {
    return f32 ? ((const float*)X)[i] : __bfloat162float(((const __hip_bfloat16*)X)[i]);
}

// ---------------------------------------------------------------------------
// Megaprep (one dispatch): q convert (4096 blocks), Wq^T (256), Wc^T (256),
// Wkv^T (32), kvred build (1536): rows 0..511 = sum of 8 chunks of kv,
// 512..1023 = first chunk, 1024..1535 = last chunk (all bf16).
// ---------------------------------------------------------------------------
__global__ __launch_bounds__(256) void megaprep(const void* __restrict__ q,
                                                const void* __restrict__ kv,
                                                const void* __restrict__ Wq,
                                                const void* __restrict__ Wkv,
                                                const void* __restrict__ Wc,
                                                __hip_bfloat16* __restrict__ qbuf,
                                                __hip_bfloat16* __restrict__ WqT,
                                                __hip_bfloat16* __restrict__ WkvT,
                                                __hip_bfloat16* __restrict__ WcT,
                                                __hip_bfloat16* __restrict__ kvred,
                                                const int* __restrict__ flag) {
    __shared__ float t[64][65];
    const int b = blockIdx.x;
    const int f32 = flag[0];
    const int tid = threadIdx.x;

    if (b < 4096) {
        int i = (b * 256 + tid) * 4;
        if (f32) {
            float4 v = *(const float4*)((const float*)q + i);
            __hip_bfloat162 tmp[2] = {__float22bfloat162_rn({v.x, v.y}),
                                      __float22bfloat162_rn({v.z, v.w})};
            *(short4*)((short*)qbuf + i) = *(const short4*)tmp;
        } else {
            *(short4*)((short*)qbuf + i) = *(const short4*)((const short*)q + i);
        }
    } else if (b < 4640) {
        const void* W;
        __hip_bfloat16* WT;
        int K = 1024, N, n0, k0;
        if (b < 4352) {
            int bx = b - 4096; W = Wq; WT = WqT; N = 1024;
            n0 = (bx & 15) * 64; k0 = (bx >> 4) * 64;
        } else if (b < 4608) {
            int bx = b - 4352; W = Wc; WT = WcT; N = 1024;
            n0 = (bx & 15) * 64; k0 = (bx >> 4) * 64;
        } else {
            int bx = b - 4608; W = Wkv; WT = WkvT; N = 128;
            n0 = (bx & 1) * 64; k0 = (bx >> 1) * 64;
        }
        const int tx = tid & 63;
        const int ty = tid >> 6;
#pragma unroll
        for (int r = 0; r < 16; ++r) {
            int k = ty + r * 4;
            t[k][tx] = ldf(W, (size_t)(k0 + k) * N + n0 + tx, f32);
        }
        __syncthreads();
#pragma unroll
        for (int r = 0; r < 16; ++r) {
            int n = ty + r * 4;
            WT[(size_t)(n0 + n) * K + k0 + tx] = __float2bfloat16(t[tx][n]);
        }
    } else {
        int y2 = b - 4640;          // 0..1535
        int c = tid * 4;
        float a0 = 0.f, a1 = 0.f, a2 = 0.f, a3 = 0.f;
        if (y2 < 512) {
#pragma unroll
            for (int z = 0; z < C_; ++z) {
                size_t base = (size_t)(z * W_ + y2) * 1024 + c;
                a0 += ldf(kv, base + 0, f32);
                a1 += ldf(kv, base + 1, f32);
                a2 += ldf(kv, base + 2, f32);
                a3 += ldf(kv, base + 3, f32);
            }
        } else {
            int row = (y2 < 1024) ? (y2 - 512) : (3584 + y2 - 1024);
            size_t base = (size_t)row * 1024 + c;
            a0 = ldf(kv, base + 0, f32);
            a1 = ldf(kv, base + 1, f32);
            a2 = ldf(kv, base + 2, f32);
            a3 = ldf(kv, base + 3, f32);
        }
        __hip_bfloat162 tmp[2] = {__float22bfloat162_rn({a0, a1}),
                                  __float22bfloat162_rn({a2, a3})};
        *(short4*)((short*)kvred + (size_t)y2 * 1024 + c) = *(const short4*)tmp;
    }
}

// ---------------------------------------------------------------------------
// MFMA GEMM: C[M,N] = alpha * A[M,K] @ BT[N,K]^T, bf16 in, fp32 accum.
// 128x64 tile, BK=64 (two BK=32 sub-tiles). plain=0: XCD swizzle mapping.
// cMode: 0 = follow flag (fp32 if flag else bf16), 1 = fp32, 2 = bf16
// ---------------------------------------------------------------------------
__global__ __launch_bounds__(256) void gemm_bt_mfma(const __hip_bfloat16* __restrict__ A,
                                                    const __hip_bfloat16* __restrict__ BT,
                                                    void* __restrict__ C,
                                                    int M, int N, int K, float alpha,
                                                    int cMode, int ntiles, int plain,
                                                    const int* __restrict__ flag) {
    __shared__ __hip_bfloat16 Asl[2][128 * 32];
    __shared__ __hip_bfloat16 Bsl[2][64 * 32];

    const int bid = blockIdx.x;
    int mt, nt;
    if (plain) { mt = bid / ntiles; nt = bid % ntiles; }
    else {
        int g = bid / (8 * ntiles);
        int rem = bid % (8 * ntiles);
        mt = g * 8 + (rem & 7);
        nt = rem >> 3;
    }
    const int m0 = mt * 128;
    const int n0 = nt * 64;

    const int tid = threadIdx.x;
    const int lane = tid & 63;
    const int wv = tid >> 6;
    const int wm = wv >> 1;
    const int wn = wv & 1;
    const int col = lane & 15;
    const int quad = lane >> 4;

    const int srow = lane >> 2;
    const int scol = (lane & 3) * 8;
    const __hip_bfloat16* Ag = A + (size_t)m0 * K;
    const __hip_bfloat16* Bg = BT + (size_t)n0 * K;

    f32x4 acc[4][2] = {};

    for (int k0 = 0; k0 < K; k0 += 64) {
#pragma unroll
        for (int h = 0; h < 2; ++h) {
            int arow = wv * 32 + h * 16 + srow;
#pragma unroll
            for (int kc = 0; kc < 2; ++kc)
                async16(Ag + (size_t)arow * K + k0 + kc * 32 + scol,
                        &Asl[kc][arow * 32 + scol]);
        }
        {
            int brow = wv * 16 + srow;
#pragma unroll
            for (int kc = 0; kc < 2; ++kc)
                async16(Bg + (size_t)brow * K + k0 + kc * 32 + scol,
                        &Bsl[kc][brow * 32 + scol]);
        }
        __syncthreads();

#pragma unroll
        for (int kc = 0; kc < 2; ++kc) {
            short8 af[4], bfr[2];
#pragma unroll
            for (int i = 0; i < 4; ++i)
                af[i] = *(const short8*)(&Asl[kc][(wm * 64 + i * 16 + col) * 32 + quad * 8]);
#pragma unroll
            for (int j = 0; j < 2; ++j)
                bfr[j] = *(const short8*)(&Bsl[kc][(wn * 32 + j * 16 + col) * 32 + quad * 8]);
#pragma unroll
            for (int am = 0; am < 4; ++am)
#pragma unroll
                for (int bn = 0; bn < 2; ++bn)
                    acc[am][bn] = __builtin_amdgcn_mfma_f32_16x16x32_bf16(af[am], bfr[bn], acc[am][bn], 0, 0, 0);
        }
        __syncthreads();
    }

    int cF = (cMode == 1) ? 1 : ((cMode == 2) ? 0 : flag[0]);
#pragma unroll
    for (int am = 0; am < 4; ++am)
#pragma unroll
        for (int bn = 0; bn < 2; ++bn)
#pragma unroll
            for (int r = 0; r < 4; ++r) {
                size_t ci = (size_t)(m0 + wm * 64 + am * 16 + quad * 4 + r) * N
                            + n0 + wn * 32 + bn * 16 + col;
                float v = acc[am][bn][r] * alpha;
                if (cF) ((float*)C)[ci] = v;
                else ((__hip_bfloat16*)C)[ci] = __float2bfloat16(v);
            }
}

// ---------------------------------------------------------------------------
// Combine kvp_red [1536][128] fp32 -> bf16 Kb [1536][64] and Vt [64][1536]
// with the R8 key permutation within 64-groups: p = ((i&15)<<2) | (i>>4),
// matching attn P LDS layout (pos = col*4 + f).
// ---------------------------------------------------------------------------
__global__ __launch_bounds__(256) void sums_kernel(const float* __restrict__ kvp_red,
                                                   __hip_bfloat16* __restrict__ Kb,
                                                   __hip_bfloat16* __restrict__ Vt) {
    int t = blockIdx.x * 256 + threadIdx.x;
    int d = t & 63;
    int y = t >> 6;

    float kc = kvp_red[(size_t)y * 128 + d];
    float kf = kvp_red[(size_t)(512 + y) * 128 + d];
    float kl = kvp_red[(size_t)(1024 + y) * 128 + d];
    float vc = kvp_red[(size_t)y * 128 + 64 + d];
    float vf = kvp_red[(size_t)(512 + y) * 128 + 64 + d];
    float vl = kvp_red[(size_t)(1024 + y) * 128 + 64 + d];

    float kvals[3] = {kc - kl, kc, kc - kf};
    float vvals[3] = {vc - vl, vc, vc - vf};
#pragma unroll
    for (int e = 0; e < 3; ++e) {
        int key = e * W_ + y;
        Kb[(size_t)key * 64 + d] = __float2bfloat16(kvals[e]);
        int g = key >> 6;
        int i = key & 63;
        int p = ((i & 15) << 2) | (i >> 4);
        Vt[(size_t)d * W3_ + g * 64 + p] = __float2bfloat16(vvals[e]);
    }
}

// ---------------------------------------------------------------------------
// Flash MFMA attention — exact R8 structure (64.4 µs measured; VGPR 128, no
// spills). Block = 64 rows, 4 waves key-split (384 keys each), Q persistent
// in regs, fixed-max exp2 softmax, P via wave-private LDS (in-order DS, no
// barrier), LDS reduction epilogue. DO NOT add register-hungry prefetch here:
// R9 (operand swap) and R10 (K dbuf) both regressed — R10 via scratch spills
// (WRITE_SIZE 417 MB).
// ---------------------------------------------------------------------------
#define PSTRIDE 72
__global__ __launch_bounds__(256, 2) void attn_kernel(const __hip_bfloat16* __restrict__ qb,
                                                      const __hip_bfloat16* __restrict__ Kb,
                                                      const __hip_bfloat16* __restrict__ Vt,
                                                      __hip_bfloat16* __restrict__ ctx) {
    __shared__ __align__(16) char smem[36864 + 1024];
    float* Ls = (float*)smem;
    float* lsum = (float*)(smem + 36864);

    const int tid = threadIdx.x;
    const int lane = tid & 63;
    const int wv = tid >> 6;
    const int m0 = blockIdx.x * 64;
    const int col = lane & 15;
    const int quad = lane >> 4;
    __hip_bfloat16* pw = (__hip_bfloat16*)smem + wv * (64 * PSTRIDE);

    short8 qf[4][2];
#pragma unroll
    for (int rg = 0; rg < 4; ++rg) {
        const __hip_bfloat16* qp = qb + (size_t)(m0 + rg * 16 + col) * 64 + quad * 8;
        qf[rg][0] = *(const short8*)(qp);
        qf[rg][1] = *(const short8*)(qp + 32);
    }

    f32x4 O[4][4] = {};
    float lrow[4][4] = {};

    for (int t = 0; t < 6; ++t) {
        const int kt = wv * 384 + t * 64;

        short8 kb0[4], kb1[4];
#pragma unroll
        for (int f = 0; f < 4; ++f) {
            const __hip_bfloat16* kp = Kb + (size_t)(kt + f * 16 + col) * 64 + quad * 8;
            kb0[f] = *(const short8*)(kp);
            kb1[f] = *(const short8*)(kp + 32);
        }

#pragma unroll
        for (int rg = 0; rg < 4; ++rg) {
            f32x4 S[4];
#pragma unroll
            for (int f = 0; f < 4; ++f) {
                f32x4 s = {};
                s = __builtin_amdgcn_mfma_f32_16x16x32_bf16(qf[rg][0], kb0[f], s, 0, 0, 0);
                s = __builtin_amdgcn_mfma_f32_16x16x32_bf16(qf[rg][1], kb1[f], s, 0, 0, 0);
                S[f] = s;
            }
#pragma unroll
            for (int f = 0; f < 4; ++f)
#pragma unroll
                for (int r = 0; r < 4; ++r) S[f][r] = FEXP2(S[f][r]);
#pragma unroll
            for (int r = 0; r < 4; ++r)
                lrow[rg][r] += (S[0][r] + S[1][r]) + (S[2][r] + S[3][r]);
#pragma unroll
            for (int r = 0; r < 4; ++r) {
                __hip_bfloat162 p01 = __float22bfloat162_rn({S[0][r], S[1][r]});
                __hip_bfloat162 p23 = __float22bfloat162_rn({S[2][r], S[3][r]});
                short4 t4;
                *(__hip_bfloat162*)(&t4.x) = p01;
                *(__hip_bfloat162*)(&t4.z) = p23;
                *(short4*)(pw + (rg * 16 + quad * 4 + r) * PSTRIDE + col * 4) = t4;
            }
        }

        short8 vb0[4], vb1[4];
#pragma unroll
        for (int f = 0; f < 4; ++f) {
            const __hip_bfloat16* vp = Vt + (size_t)(f * 16 + col) * W3_ + kt + quad * 8;
            vb0[f] = *(const short8*)(vp);
            vb1[f] = *(const short8*)(vp + 32);
        }

#pragma unroll
        for (int rg = 0; rg < 4; ++rg) {
            short8 a0 = *(const short8*)(pw + (rg * 16 + col) * PSTRIDE + quad * 8);
            short8 a1 = *(const short8*)(pw + (rg * 16 + col) * PSTRIDE + 32 + quad * 8);
#pragma unroll
            for (int f = 0; f < 4; ++f) {
                O[rg][f] = __builtin_amdgcn_mfma_f32_16x16x32_bf16(a0, vb0[f], O[rg][f], 0, 0, 0);
                O[rg][f] = __builtin_amdgcn_mfma_f32_16x16x32_bf16(a1, vb1[f], O[rg][f], 0, 0, 0);
            }
        }
    }

#pragma unroll
    for (int msk = 1; msk <= 8; msk <<= 1)
#pragma unroll
        for (int rg = 0; rg < 4; ++rg)
#pragma unroll
            for (int r = 0; r < 4; ++r) lrow[rg][r] += __shfl_xor(lrow[rg][r], msk, 64);

    __syncthreads();

    if (col == 0) {
#pragma unroll
        for (int rg = 0; rg < 4; ++rg)
#pragma unroll
            for (int r = 0; r < 4; ++r)
                lsum[wv * 64 + rg * 16 + quad * 4 + r] = lrow[rg][r];
    }

#pragma unroll
    for (int half = 0; half < 2; ++half) {
#pragma unroll
        for (int g = 0; g < 2; ++g) {
            int rg = half * 2 + g;
#pragma unroll
            for (int f = 0; f < 4; ++f)
#pragma unroll
                for (int r = 0; r < 4; ++r)
                    Ls[(wv * 32 + g * 16 + quad * 4 + r) * 66 + f * 16 + col] = O[rg][f][r];
        }
        __syncthreads();
#pragma unroll
        for (int i = 0; i < 8; ++i) {
            int r32 = wv * 8 + i;
            int row = half * 32 + r32;
            float tot = Ls[(0 * 32 + r32) * 66 + lane]
                      + Ls[(1 * 32 + r32) * 66 + lane]
                      + Ls[(2 * 32 + r32) * 66 + lane]
                      + Ls[(3 * 32 + r32) * 66 + lane];
            float ltot = lsum[0 * 64 + row] + lsum[1 * 64 + row]
                       + lsum[2 * 64 + row] + lsum[3 * 64 + row];
            ctx[(size_t)(m0 + row) * 64 + lane] = __float2bfloat16(tot * (1.f / ltot));
        }
        __syncthreads();
    }
}

// ---------------------------------------------------------------------------
// Launch
// ---------------------------------------------------------------------------
extern "C" void kernel_launch(void* const* d_in, const int* in_sizes, int n_in,
                              void* d_out, int out_size, void* d_ws, size_t ws_size,
                              hipStream_t stream) {
    const void* q   = d_in[0];
    const void* kv  = d_in[1];
    const void* Wq  = d_in[2];
    const void* Wkv = d_in[3];
    const void* Wc  = d_in[4];

    char* ws = (char*)d_ws;
    size_t off = 0;
    int* flag = (int*)(ws + off); off += 1024;
    __hip_bfloat16* qbuf   = (__hip_bfloat16*)(ws + off); off += (size_t)L_ * DM_ * 2;     // 8 MB
    __hip_bfloat16* WqT    = (__hip_bfloat16*)(ws + off); off += (size_t)DM_ * DM_ * 2;    // 2 MB
    __hip_bfloat16* WkvT   = (__hip_bfloat16*)(ws + off); off += (size_t)128 * DM_ * 2;    // 256 KB
    __hip_bfloat16* WcT    = (__hip_bfloat16*)(ws + off); off += (size_t)DM_ * DM_ * 2;    // 2 MB
    __hip_bfloat16* qb     = (__hip_bfloat16*)(ws + off); off += (size_t)L_ * DM_ * 2;     // 8 MB
    __hip_bfloat16* kvred  = (__hip_bfloat16*)(ws + off); off += (size_t)1536 * 1024 * 2;  // 3 MB
    float*          kvpred = (float*)(ws + off);          off += (size_t)1536 * 128 * 4;   // 768 KB
    __hip_bfloat16* Kb     = (__hip_bfloat16*)(ws + off); off += (size_t)W3_ * 64 * 2;     // 192 KB
    __hip_bfloat16* Vt     = (__hip_bfloat16*)(ws + off); off += (size_t)64 * W3_ * 2;     // 192 KB
    __hip_bfloat16* ctxb   = (__hip_bfloat16*)(ws + off);                                  // 8 MB

    detect_kernel<<<1, 256, 0, stream>>>((const uint4*)q, flag);

    megaprep<<<6176, 256, 0, stream>>>(q, kv, Wq, Wkv, Wc,
                                       qbuf, WqT, WkvT, WcT, kvred, flag);

    // qb = (q @ Wq) * (1/8)*log2(e), bf16 (exp2-domain logits)
    gemm_bt_mfma<<<512, 256, 0, stream>>>(qbuf, WqT, qb, L_, DM_, DM_,
                                          0.125f * 1.44269504f, 2, 16, 0, flag);
    // kvp_red = kvred @ Wkv, fp32  (M=1536 after chunk-sum commutation)
    gemm_bt_mfma<<<24, 256, 0, stream>>>(kvred, WkvT, kvpred, 1536, 128, DM_,
                                         1.0f, 1, 2, 1, flag);
    sums_kernel<<<128, 256, 0, stream>>>(kvpred, Kb, Vt);
    attn_kernel<<<dim3(NROWS_ / 64), 256, 0, stream>>>(qb, Kb, Vt, ctxb);
    // out = ctx @ Wc, dtype per flag
    gemm_bt_mfma<<<512, 256, 0, stream>>>(ctxb, WcT, d_out, L_, DM_, DM_,
                                          1.0f, 0, 16, 0, flag);
}